// Round 2
// baseline (826.300 us; speedup 1.0000x reference)
//
#include <hip/hip_runtime.h>
#include <hip/hip_bf16.h>

#define KOFF        8
#define M_PAIRS     262144        // pairs per offset
#define NOUT_SITES  524288
#define NCIN        32
#define NCOUT       64
#define BN_EPS      1e-4f
#define LEAK        (1.0f / 3.0f)

typedef __attribute__((ext_vector_type(8))) short bf16x8;
typedef __attribute__((ext_vector_type(4))) float f32x4;

__device__ __forceinline__ short f2bf(float f) {
    union { float f; unsigned u; } v; v.f = f;
    unsigned r = v.u + 0x7fffu + ((v.u >> 16) & 1u);   // RTNE
    return (short)(r >> 16);
}

// ---------------------------------------------------------------------------
// Conv: gather -> bf16 MFMA (16x16x32) -> coalesced atomic scatter-add
// grid: 8192 blocks of 256 (1024 blocks per offset k); each wave does 4 iters
// of 16 pairs (256 pairs/block).
// ---------------------------------------------------------------------------
__global__ __launch_bounds__(256) void conv_scatter_kernel(
    const float* __restrict__ feats,
    const float* __restrict__ W,
    const int*   __restrict__ in_idx,
    const int*   __restrict__ out_idx,
    float*       __restrict__ out)
{
    const int lane = threadIdx.x & 63;
    const int wave = threadIdx.x >> 6;
    const int lr   = lane & 15;   // row (A) / col (B,D)
    const int lg   = lane >> 4;   // k-chunk / row-group
    const int k    = blockIdx.x >> 10;
    const int pair_base = ((blockIdx.x & 1023) << 8) + (wave << 6);

    // B fragments: lane holds W[k][lg*8+j][cb*16+lr], j=0..7, for 4 col-blocks
    const float* Wk = W + k * (NCIN * NCOUT);
    bf16x8 bfrag[4];
#pragma unroll
    for (int cb = 0; cb < 4; ++cb) {
#pragma unroll
        for (int j = 0; j < 8; ++j)
            bfrag[cb][j] = f2bf(Wk[(lg * 8 + j) * NCOUT + cb * 16 + lr]);
    }

    const int* in_k  = in_idx  + k * M_PAIRS;
    const int* out_k = out_idx + k * M_PAIRS;

#pragma unroll 1
    for (int it = 0; it < 4; ++it) {
        const int p0 = pair_base + (it << 4);

        // A fragment: pair row = lr, k-elems lg*8 .. lg*8+7
        const int irow = in_k[p0 + lr];
        const float* fp = feats + (size_t)irow * NCIN + lg * 8;
        f32x4 f0 = *(const f32x4*)fp;
        f32x4 f1 = *(const f32x4*)(fp + 4);
        bf16x8 af;
        af[0] = f2bf(f0[0]); af[1] = f2bf(f0[1]);
        af[2] = f2bf(f0[2]); af[3] = f2bf(f0[3]);
        af[4] = f2bf(f1[0]); af[5] = f2bf(f1[1]);
        af[6] = f2bf(f1[2]); af[7] = f2bf(f1[3]);

        const f32x4 zero = {0.f, 0.f, 0.f, 0.f};
        f32x4 acc[4];
#pragma unroll
        for (int cb = 0; cb < 4; ++cb)
            acc[cb] = __builtin_amdgcn_mfma_f32_16x16x32_bf16(af, bfrag[cb], zero, 0, 0, 0);

        // D layout: pair = lg*4 + r, channel = cb*16 + lr  -> lanes cover 16
        // consecutive channels of 4 rows per instruction (cacheline-coalesced)
        int orow[4];
#pragma unroll
        for (int r = 0; r < 4; ++r)
            orow[r] = out_k[p0 + lg * 4 + r];
#pragma unroll
        for (int r = 0; r < 4; ++r) {
            float* op = out + (size_t)orow[r] * NCOUT + lr;
#pragma unroll
            for (int cb = 0; cb < 4; ++cb)
                unsafeAtomicAdd(op + cb * 16, acc[cb][r]);
        }
    }
}

// ---------------------------------------------------------------------------
// BN stats: per-channel sum & sumsq over all sites.
// Thread's float4 index keeps a fixed channel phase (i % 16) since all
// strides are multiples of 16 float4s (64 channels).
// ---------------------------------------------------------------------------
__global__ __launch_bounds__(256) void bn_stats_kernel(
    const float* __restrict__ out, float* __restrict__ stats)
{
    const int tid    = blockIdx.x * 256 + threadIdx.x;
    const int stride = gridDim.x * 256;
    const int total4 = NOUT_SITES * NCOUT / 4;

    float s[4] = {0.f, 0.f, 0.f, 0.f};
    float q[4] = {0.f, 0.f, 0.f, 0.f};
    for (int i = tid; i < total4; i += stride) {
        f32x4 v = ((const f32x4*)out)[i];
#pragma unroll
        for (int j = 0; j < 4; ++j) { s[j] += v[j]; q[j] += v[j] * v[j]; }
    }

    // lanes l, l^16, l^32, l^48 share the same channel phase (lane & 15)
#pragma unroll
    for (int off = 16; off <= 32; off <<= 1) {
#pragma unroll
        for (int j = 0; j < 4; ++j) {
            s[j] += __shfl_xor(s[j], off);
            q[j] += __shfl_xor(q[j], off);
        }
    }

    __shared__ float red[4][16][8];
    const int lane = threadIdx.x & 63;
    const int wave = threadIdx.x >> 6;
    if (lane < 16) {
#pragma unroll
        for (int j = 0; j < 4; ++j) {
            red[wave][lane][j]     = s[j];
            red[wave][lane][4 + j] = q[j];
        }
    }
    __syncthreads();

    const int t = threadIdx.x;
    if (t < 128) {
        const int phase = t >> 3, j = t & 7;
        float v = red[0][phase][j] + red[1][phase][j] +
                  red[2][phase][j] + red[3][phase][j];
        const int ch = phase * 4 + (j & 3);
        unsafeAtomicAdd(&stats[(j < 4) ? ch : (64 + ch)], v);
    }
}

__global__ void bn_finalize_kernel(float* __restrict__ stats,
                                   const float* __restrict__ gamma,
                                   const float* __restrict__ beta)
{
    const int c = threadIdx.x;
    if (c < NCOUT) {
        const float n    = (float)NOUT_SITES;
        const float mean = stats[c] / n;
        const float var  = stats[64 + c] / n - mean * mean;
        const float sc   = gamma[c] * rsqrtf(var + BN_EPS);
        stats[128 + c] = sc;
        stats[192 + c] = beta[c] - mean * sc;
    }
}

__global__ __launch_bounds__(256) void bn_lrelu_kernel(
    float* __restrict__ out, const float* __restrict__ stats)
{
    const int tid    = blockIdx.x * 256 + threadIdx.x;
    const int stride = gridDim.x * 256;
    const int total4 = NOUT_SITES * NCOUT / 4;
    const int phase  = threadIdx.x & 15;

    const f32x4 sc = ((const f32x4*)(stats + 128))[phase];
    const f32x4 sh = ((const f32x4*)(stats + 192))[phase];

    for (int i = tid; i < total4; i += stride) {
        f32x4 v = ((const f32x4*)out)[i];
        f32x4 h;
#pragma unroll
        for (int j = 0; j < 4; ++j) {
            float x = v[j] * sc[j] + sh[j];
            h[j] = x > 0.f ? x : x * LEAK;
        }
        ((f32x4*)out)[i] = h;
    }
}

extern "C" void kernel_launch(void* const* d_in, const int* in_sizes, int n_in,
                              void* d_out, int out_size, void* d_ws, size_t ws_size,
                              hipStream_t stream)
{
    const float* feats   = (const float*)d_in[0];
    const float* W       = (const float*)d_in[1];
    const float* gamma   = (const float*)d_in[2];
    const float* beta    = (const float*)d_in[3];
    const int*   in_idx  = (const int*)d_in[4];
    const int*   out_idx = (const int*)d_in[5];
    float*       out     = (float*)d_out;
    float*       stats   = (float*)d_ws;

    // zero the scatter accumulator (d_out doubles as accumulator) and stats
    hipMemsetAsync(d_out, 0, (size_t)NOUT_SITES * NCOUT * sizeof(float), stream);
    hipMemsetAsync(d_ws, 0, 128 * sizeof(float), stream);

    conv_scatter_kernel<<<8192, 256, 0, stream>>>(feats, W, in_idx, out_idx, out);
    bn_stats_kernel<<<1024, 256, 0, stream>>>(out, stats);
    bn_finalize_kernel<<<1, 64, 0, stream>>>(stats, gamma, beta);
    bn_lrelu_kernel<<<2048, 256, 0, stream>>>(out, stats);
}